// Round 5
// baseline (100.132 us; speedup 1.0000x reference)
//
#include <hip/hip_runtime.h>
#include <hip/hip_bf16.h>

// DotPredictor: out[e] = dot(h[src[e]], h[dst[e]]), D=64.
// R5: int8 per-row scale (R4, absmax 0.44 < 1.54) + MLP test: each 4-lane
// group now handles TWO edges -> 4 independent row loads in flight per
// thread, half the waves, same transaction count/coalescing (4 lanes x 16 B
// = one 64-B request per row). Distinguishes latency-bound vs
// transaction-bound gather. Fixed harness floor ~65 us (d_ws re-poison).

#define D_FEAT 64

#if defined(__has_builtin)
#if __has_builtin(__builtin_amdgcn_sdot4)
#define HAVE_SDOT4 1
#endif
#endif

__device__ __forceinline__ int dot4_i8(unsigned a, unsigned b, int c) {
#ifdef HAVE_SDOT4
    return __builtin_amdgcn_sdot4((int)a, (int)b, c, false);
#else
    int s = c;
    s += ((int)(a << 24) >> 24) * ((int)(b << 24) >> 24);
    s += ((int)(a << 16) >> 24) * ((int)(b << 16) >> 24);
    s += ((int)(a <<  8) >> 24) * ((int)(b <<  8) >> 24);
    s += ((int)(a      ) >> 24) * ((int)(b      ) >> 24);
    return s;
#endif
}

__device__ __forceinline__ int quant1(float x, float inv) {
    int q = __float2int_rn(x * inv);
    return min(max(q, -127), 127);
}

// 16 lanes per row; lane loads float4, 4-step shfl max-reduce within the
// 16-lane group, quantize 4 values -> 1 dword, write. sub==0 writes scale.
__global__ void quant_rows_i8(const float* __restrict__ h,
                              unsigned* __restrict__ hq,      // row = 16 dwords
                              float* __restrict__ scale,      // row -> rowmax/127
                              int n_rows) {
    const int tid = blockIdx.x * blockDim.x + threadIdx.x;
    const int row = tid >> 4;
    const int sub = tid & 15;
    if (row >= n_rows) return;

    const float4 v = *reinterpret_cast<const float4*>(
        h + (size_t)row * D_FEAT + sub * 4);

    float m = fmaxf(fmaxf(fabsf(v.x), fabsf(v.y)),
                    fmaxf(fabsf(v.z), fabsf(v.w)));
    m = fmaxf(m, __shfl_xor(m, 1));
    m = fmaxf(m, __shfl_xor(m, 2));
    m = fmaxf(m, __shfl_xor(m, 4));
    m = fmaxf(m, __shfl_xor(m, 8));      // m = rowmax over all 64 elems

    const float inv = (m > 0.f) ? (127.0f / m) : 0.f;

    unsigned w = (unsigned)(quant1(v.x, inv) & 0xff)
               | ((unsigned)(quant1(v.y, inv) & 0xff) << 8)
               | ((unsigned)(quant1(v.z, inv) & 0xff) << 16)
               | ((unsigned)(quant1(v.w, inv) & 0xff) << 24);
    hq[(size_t)row * 16 + sub] = w;

    if (sub == 0) scale[row] = m * (1.0f / 127.0f);
}

// 4 lanes per 2 edges: each thread carries 4 independent uint4 row loads
// (2 edges x 2 operands) -> 4-deep MLP; exact int shfl reduction; lane 0
// writes both outputs as one float2.
__global__ void edge_dot_i8x2(const unsigned* __restrict__ hq,
                              const float* __restrict__ scale,
                              const int* __restrict__ src,
                              const int* __restrict__ dst,
                              float* __restrict__ out,
                              int n_edges) {
    const int tid = blockIdx.x * blockDim.x + threadIdx.x;
    const int g   = tid >> 2;            // group handles edges 2g, 2g+1
    const int sub = threadIdx.x & 3;
    const int e0  = g * 2;
    if (e0 >= n_edges) return;
    const int e1   = e0 + 1;
    const bool has1 = (e1 < n_edges);

    const int s0 = src[e0], d0 = dst[e0];
    const int s1 = has1 ? src[e1] : s0;
    const int d1 = has1 ? dst[e1] : d0;

    const uint4* hq4 = reinterpret_cast<const uint4*>(hq);  // row = 4 uint4
    const uint4 a0 = hq4[(size_t)s0 * 4 + sub];
    const uint4 b0 = hq4[(size_t)d0 * 4 + sub];
    const uint4 a1 = hq4[(size_t)s1 * 4 + sub];
    const uint4 b1 = hq4[(size_t)d1 * 4 + sub];

    int acc0 = 0, acc1 = 0;
    acc0 = dot4_i8(a0.x, b0.x, acc0);
    acc0 = dot4_i8(a0.y, b0.y, acc0);
    acc0 = dot4_i8(a0.z, b0.z, acc0);
    acc0 = dot4_i8(a0.w, b0.w, acc0);
    acc1 = dot4_i8(a1.x, b1.x, acc1);
    acc1 = dot4_i8(a1.y, b1.y, acc1);
    acc1 = dot4_i8(a1.z, b1.z, acc1);
    acc1 = dot4_i8(a1.w, b1.w, acc1);

    acc0 += __shfl_xor(acc0, 1);
    acc0 += __shfl_xor(acc0, 2);
    acc1 += __shfl_xor(acc1, 1);
    acc1 += __shfl_xor(acc1, 2);

    if (sub == 0) {
        const float o0 = (float)acc0 * scale[s0] * scale[d0];
        if (has1) {
            const float o1 = (float)acc1 * scale[s1] * scale[d1];
            *reinterpret_cast<float2*>(out + e0) = make_float2(o0, o1);
        } else {
            out[e0] = o0;
        }
    }
}

// Fallback (f32 path) if workspace is too small for the int8 copy of h.
__global__ void edge_dot_f32(const float* __restrict__ h,
                             const int* __restrict__ src,
                             const int* __restrict__ dst,
                             float* __restrict__ out,
                             int n_edges) {
    const int tid  = blockIdx.x * blockDim.x + threadIdx.x;
    const int edge = tid >> 4;
    const int sub  = threadIdx.x & 15;
    if (edge >= n_edges) return;
    const int s = src[edge];
    const int d = dst[edge];
    const float4 a = *reinterpret_cast<const float4*>(h + (size_t)s * D_FEAT + sub * 4);
    const float4 b = *reinterpret_cast<const float4*>(h + (size_t)d * D_FEAT + sub * 4);
    float p = a.x * b.x + a.y * b.y + a.z * b.z + a.w * b.w;
    p += __shfl_xor(p, 1);
    p += __shfl_xor(p, 2);
    p += __shfl_xor(p, 4);
    p += __shfl_xor(p, 8);
    if (sub == 0) out[edge] = p;
}

extern "C" void kernel_launch(void* const* d_in, const int* in_sizes, int n_in,
                              void* d_out, int out_size, void* d_ws, size_t ws_size,
                              hipStream_t stream) {
    const float* h   = (const float*)d_in[0];
    const int*   src = (const int*)d_in[1];
    const int*   dst = (const int*)d_in[2];
    float*       out = (float*)d_out;

    const int n_nodes = in_sizes[0] / D_FEAT;   // 100,000
    const int n_edges = in_sizes[1];            // 1,000,000

    const size_t hq_bytes    = (size_t)n_nodes * D_FEAT;          // 6.4 MB
    const size_t scale_bytes = (size_t)n_nodes * sizeof(float);   // 400 KB

    if (ws_size >= hq_bytes + scale_bytes) {
        unsigned* hq    = (unsigned*)d_ws;
        float*    scale = (float*)((char*)d_ws + hq_bytes);

        const int qthreads = n_nodes * 16;
        quant_rows_i8<<<(qthreads + 255) / 256, 256, 0, stream>>>(
            h, hq, scale, n_nodes);

        const int ngroups = (n_edges + 1) / 2;       // 2 edges per 4-lane group
        const int threads = ngroups * 4;
        edge_dot_i8x2<<<(threads + 255) / 256, 256, 0, stream>>>(
            hq, scale, src, dst, out, n_edges);
    } else {
        const int threads = n_edges * 16;
        edge_dot_f32<<<(threads + 255) / 256, 256, 0, stream>>>(
            h, src, dst, out, n_edges);
    }
}